// Round 8
// baseline (732.593 us; speedup 1.0000x reference)
//
#include <hip/hip_runtime.h>
#include <hip/hip_fp16.h>

#define CG_N      8192
#define CG_ITERS  10

// symmetric (upper-triangle) matvec geometry
#define BAND      128
#define NBANDS    64                          // CG_N / BAND
#define NTILES    (NBANDS * (NBANDS + 1) / 2) // 2080 upper tiles
#define MV_BLOCKS 256

// convert kernel geometry (fp32 A, iteration 0)
#define RPW_C       4
#define WPB_C       4
#define CONV_BLOCKS (CG_N / (RPW_C * WPB_C))   // 512
#define NW_CONV     (CG_N / RPW_C)             // 2048 pAp slots

// ---------------------------------------------------------------------------
// x = 0, r = b, p = b, rs_part[block] = block partial of b.b  (plain stores)
// ---------------------------------------------------------------------------
__global__ __launch_bounds__(256) void cg_init_kernel(const float* __restrict__ b,
                                                      float* __restrict__ x,
                                                      float* __restrict__ r,
                                                      float* __restrict__ p,
                                                      float* __restrict__ rs_part) {
    const int i = blockIdx.x * 256 + threadIdx.x;   // float4 index
    const float4 bv = reinterpret_cast<const float4*>(b)[i];
    reinterpret_cast<float4*>(x)[i] = make_float4(0.f, 0.f, 0.f, 0.f);
    reinterpret_cast<float4*>(r)[i] = bv;
    reinterpret_cast<float4*>(p)[i] = bv;

    float v = bv.x * bv.x + bv.y * bv.y + bv.z * bv.z + bv.w * bv.w;
#pragma unroll
    for (int off = 32; off > 0; off >>= 1) v += __shfl_down(v, off);
    __shared__ float tmp[4];
    const int t = threadIdx.x;
    if ((t & 63) == 0) tmp[t >> 6] = v;
    __syncthreads();
    if (t == 0) rs_part[blockIdx.x] = tmp[0] + tmp[1] + tmp[2] + tmp[3];
}

__device__ __forceinline__ unsigned pack2h(float a, float b) {
    const __half2 h = __floats2half2_rn(a, b);
    return *reinterpret_cast<const unsigned*>(&h);
}

__device__ __forceinline__ float4 syn4(float beta, float4 pv, float4 rv) {
    float4 o;
    o.x = fmaf(beta, pv.x, rv.x); o.y = fmaf(beta, pv.y, rv.y);
    o.z = fmaf(beta, pv.z, rv.z); o.w = fmaf(beta, pv.w, rv.w);
    return o;
}

// ---------------------------------------------------------------------------
// Iteration-0 matvec (fp32 A) + conversion to fp16.
//   y = (A + 1e-6 I) p ; per-wave slot store of p.y
//   A16 written ONLY for upper-triangle tiles (col band >= row band);
//   diagonal extracted to fp32 diag32 and zeroed in A16.
// 512 blocks, 4 rows/wave; lane l handles column groups g = k*64+l (8 cols).
// ---------------------------------------------------------------------------
__global__ __launch_bounds__(256) void cg_matvec_convert(const float* __restrict__ A,
                                                         __half* __restrict__ A16,
                                                         float* __restrict__ diag32,
                                                         const float* __restrict__ p,
                                                         float* __restrict__ y,
                                                         float* __restrict__ pAp_s) {
    const int t    = threadIdx.x;
    const int lane = t & 63;
    const int wid  = blockIdx.x * WPB_C + (t >> 6);   // 0..2047
    const int row0 = wid * RPW_C;

    const float4* __restrict__ p4 = reinterpret_cast<const float4*>(p);
    const float4* Arow4[RPW_C];
    uint4* A16row4[RPW_C];
#pragma unroll
    for (int q = 0; q < RPW_C; ++q) {
        Arow4[q]   = reinterpret_cast<const float4*>(A + (size_t)(row0 + q) * CG_N);
        A16row4[q] = reinterpret_cast<uint4*>(A16 + (size_t)(row0 + q) * CG_N);
    }

    float acc[RPW_C] = {0.f, 0.f, 0.f, 0.f};

#pragma unroll 1
    for (int k = 0; k < 16; ++k) {
        const int g = k * 64 + lane;               // column group, 8 cols
        const float4 pa = p4[2 * g], pb = p4[2 * g + 1];
#pragma unroll
        for (int q = 0; q < RPW_C; ++q) {
            float4 a = Arow4[q][2 * g];
            float4 b = Arow4[q][2 * g + 1];
            acc[q] += a.x * pa.x + a.y * pa.y + a.z * pa.z + a.w * pa.w +
                      b.x * pb.x + b.y * pb.y + b.z * pb.z + b.w * pb.w;
            const int row = row0 + q;
            if (k == (row >> 9) && lane == ((row >> 3) & 63)) {
                const int m = row & 7;
                const float d = (m == 0) ? a.x : (m == 1) ? a.y : (m == 2) ? a.z :
                                (m == 3) ? a.w : (m == 4) ? b.x : (m == 5) ? b.y :
                                (m == 6) ? b.z : b.w;
                diag32[row] = d + 1e-6f;
                if      (m == 0) a.x = 0.f; else if (m == 1) a.y = 0.f;
                else if (m == 2) a.z = 0.f; else if (m == 3) a.w = 0.f;
                else if (m == 4) b.x = 0.f; else if (m == 5) b.y = 0.f;
                else if (m == 6) b.z = 0.f; else               b.w = 0.f;
            }
            // write only upper-triangle tiles: col band (g>>4) >= row band (row>>7)
            if ((g >> 4) >= (row >> 7)) {
                uint4 hh;
                hh.x = pack2h(a.x, a.y); hh.y = pack2h(a.z, a.w);
                hh.z = pack2h(b.x, b.y); hh.w = pack2h(b.z, b.w);
                A16row4[q][g] = hh;
            }
        }
    }

#pragma unroll
    for (int q = 0; q < RPW_C; ++q)
#pragma unroll
        for (int off = 32; off > 0; off >>= 1) acc[q] += __shfl_down(acc[q], off);

    if (lane == 0) {
        float pAp = 0.f;
#pragma unroll
        for (int q = 0; q < RPW_C; ++q) {
            const int row = row0 + q;
            const float pv = p[row];
            const float yr = acc[q] + 1e-6f * pv;   // fp32 dot included true diag
            y[row] = yr;
            pAp += yr * pv;
        }
        pAp_s[wid] = pAp;      // unique slot — plain store, deterministic
    }
}

// ---------------------------------------------------------------------------
// Symmetric fp16 matvec over upper-triangle tiles, with fused p-synthesis.
//   beta  = sum(rs_num)/sum(rs_den)+eps   (fixed order)
//   p_new = r + beta*p_old  (block writes its designated 32-float slice)
//   For each tile (bi,bj), bi<=bj, 128x128:
//     forward:   ypart[bj][row in bi]  = A_tile   . p_new[cols of bj]
//     transpose: ypart[bi][col in bj] += A_tile^T . p_new[rows of bi]  (bi<bj)
//   Entry ypart[c][idx] has exactly one writer -> deterministic.
// Wave layout: lane = rowsub*16 + cg; per trip reads 4 rows x 128 cols.
// ---------------------------------------------------------------------------
__global__ __launch_bounds__(256) void cg_matvec_ut(const __half* __restrict__ A16,
                                                    const float* __restrict__ r,
                                                    const float* __restrict__ p_old,
                                                    float* __restrict__ p_new,
                                                    float* __restrict__ ypart,
                                                    const float* __restrict__ rs_num,
                                                    const float* __restrict__ rs_den) {
    const int t      = threadIdx.x;
    const int lane   = t & 63;
    const int w      = t >> 6;         // wave 0..3
    const int rowsub = lane >> 4;      // 0..3
    const int cg     = lane & 15;      // col group (8 cols each)

    float num = 0.f, den = 0.f;
#pragma unroll
    for (int k = 0; k < 8; ++k) { num += rs_num[k]; den += rs_den[k]; }
    const float beta = num / (den + 1e-12f);

    const float4* __restrict__ r4  = reinterpret_cast<const float4*>(r);
    const float4* __restrict__ po4 = reinterpret_cast<const float4*>(p_old);

    // designated p_new writer: float4 j = bid*8 + t, t < 8 (covers all 8192)
    if (t < 8) {
        const int j = blockIdx.x * 8 + t;
        reinterpret_cast<float4*>(p_new)[j] = syn4(beta, po4[j], r4[j]);
    }

    __shared__ float tsl[4][BAND];

    for (int tile = blockIdx.x; tile < NTILES; tile += MV_BLOCKS) {
        int bi = 0, rem = tile, rl = NBANDS;
        while (rem >= rl) { rem -= rl; --rl; ++bi; }
        const int bj = bi + rem;
        const int rb = bi * BAND, cb = bj * BAND;
        const bool diag = (bi == bj);

        // this lane's 8-col slice of p_new (synthesized)
        const int c4 = (cb >> 2) + cg * 2;
        const float4 pca = syn4(beta, po4[c4],     r4[c4]);
        const float4 pcb = syn4(beta, po4[c4 + 1], r4[c4 + 1]);

        float tc0=0.f,tc1=0.f,tc2=0.f,tc3=0.f,tc4=0.f,tc5=0.f,tc6=0.f,tc7=0.f;

#pragma unroll
        for (int tr = 0; tr < 8; ++tr) {
            const int row = rb + w * 32 + tr * 4 + rowsub;
            const uint4 av = *reinterpret_cast<const uint4*>(
                A16 + (size_t)row * CG_N + cb + cg * 8);
            const __half2* h2 = reinterpret_cast<const __half2*>(&av);
            const float2 f0 = __half22float2(h2[0]);
            const float2 f1 = __half22float2(h2[1]);
            const float2 f2 = __half22float2(h2[2]);
            const float2 f3 = __half22float2(h2[3]);

            float fwd = f0.x*pca.x + f0.y*pca.y + f1.x*pca.z + f1.y*pca.w
                      + f2.x*pcb.x + f2.y*pcb.y + f3.x*pcb.z + f3.y*pcb.w;
            fwd += __shfl_down(fwd, 8);
            fwd += __shfl_down(fwd, 4);
            fwd += __shfl_down(fwd, 2);
            fwd += __shfl_down(fwd, 1);
            if (cg == 0) ypart[(size_t)bj * CG_N + row] = fwd;

            if (!diag) {
                const float prow = fmaf(beta, p_old[row], r[row]);  // p_new[row]
                tc0 = fmaf(f0.x, prow, tc0); tc1 = fmaf(f0.y, prow, tc1);
                tc2 = fmaf(f1.x, prow, tc2); tc3 = fmaf(f1.y, prow, tc3);
                tc4 = fmaf(f2.x, prow, tc4); tc5 = fmaf(f2.y, prow, tc5);
                tc6 = fmaf(f3.x, prow, tc6); tc7 = fmaf(f3.y, prow, tc7);
            }
        }

        if (!diag) {   // block-uniform branch
            tc0 += __shfl_down(tc0, 32); tc0 += __shfl_down(tc0, 16);
            tc1 += __shfl_down(tc1, 32); tc1 += __shfl_down(tc1, 16);
            tc2 += __shfl_down(tc2, 32); tc2 += __shfl_down(tc2, 16);
            tc3 += __shfl_down(tc3, 32); tc3 += __shfl_down(tc3, 16);
            tc4 += __shfl_down(tc4, 32); tc4 += __shfl_down(tc4, 16);
            tc5 += __shfl_down(tc5, 32); tc5 += __shfl_down(tc5, 16);
            tc6 += __shfl_down(tc6, 32); tc6 += __shfl_down(tc6, 16);
            tc7 += __shfl_down(tc7, 32); tc7 += __shfl_down(tc7, 16);
            if (rowsub == 0) {
                float* d = &tsl[w][cg * 8];
                d[0]=tc0; d[1]=tc1; d[2]=tc2; d[3]=tc3;
                d[4]=tc4; d[5]=tc5; d[6]=tc6; d[7]=tc7;
            }
            __syncthreads();
            if (t < BAND)
                ypart[(size_t)bi * CG_N + cb + t] =
                    tsl[0][t] + tsl[1][t] + tsl[2][t] + tsl[3][t];
            __syncthreads();
        }
    }
}

// ---------------------------------------------------------------------------
// Assemble y from the 64 per-band partials (fixed order) + diagonal term,
// and emit per-block pAp partials. grid: 32 blocks x 256 (one row/thread).
// ---------------------------------------------------------------------------
__global__ __launch_bounds__(256) void cg_assemble_kernel(const float* __restrict__ ypart,
                                                          const float* __restrict__ diag32,
                                                          const float* __restrict__ p,
                                                          float* __restrict__ y,
                                                          float* __restrict__ pap32) {
    const int row = blockIdx.x * 256 + threadIdx.x;
    float s = 0.f;
#pragma unroll
    for (int c = 0; c < NBANDS; ++c) s += ypart[(size_t)c * CG_N + row];
    const float pv = p[row];
    const float yr = fmaf(diag32[row], pv, s);
    y[row] = yr;

    float v = yr * pv;
#pragma unroll
    for (int off = 32; off > 0; off >>= 1) v += __shfl_down(v, off);
    __shared__ float tmp[4];
    if ((threadIdx.x & 63) == 0) tmp[threadIdx.x >> 6] = v;
    __syncthreads();
    if (threadIdx.x == 0) pap32[blockIdx.x] = tmp[0] + tmp[1] + tmp[2] + tmp[3];
}

// ---------------------------------------------------------------------------
// Update, fully deterministic, direct residual norm:
//   pAp   = fixed-order tree reduction of n_slots per-wave slots
//   rso   = fixed serial sum of rs_old8[0..8)
//   alpha = rso / (pAp + 1e-12)
//   x += alpha p ; r -= alpha y ; rs_new8[block] = block partial of r.r
// ---------------------------------------------------------------------------
__global__ __launch_bounds__(256) void cg_update_kernel(float* __restrict__ x,
                                                        float* __restrict__ r,
                                                        const float* __restrict__ p,
                                                        const float* __restrict__ y,
                                                        const float* __restrict__ pAp_s,
                                                        int n_slots,
                                                        const float* __restrict__ rs_old8,
                                                        float* __restrict__ rs_new8) {
    const int t = threadIdx.x;

    float a = 0.f;
    for (int k = t; k < n_slots; k += 256) a += pAp_s[k];   // fixed strided partials
#pragma unroll
    for (int off = 32; off > 0; off >>= 1) a += __shfl_down(a, off);
    __shared__ float t0[4];
    if ((t & 63) == 0) t0[t >> 6] = a;
    __syncthreads();
    const float pAp = t0[0] + t0[1] + t0[2] + t0[3];

    float rso = 0.f;
#pragma unroll
    for (int k = 0; k < 8; ++k) rso += rs_old8[k];
    const float alpha = rso / (pAp + 1e-12f);

    const int i = blockIdx.x * 256 + t;             // float4 index
    float4 xv = reinterpret_cast<float4*>(x)[i];
    float4 rv = reinterpret_cast<float4*>(r)[i];
    const float4 pv = reinterpret_cast<const float4*>(p)[i];
    const float4 yv = reinterpret_cast<const float4*>(y)[i];

    xv.x += alpha * pv.x; xv.y += alpha * pv.y; xv.z += alpha * pv.z; xv.w += alpha * pv.w;
    rv.x -= alpha * yv.x; rv.y -= alpha * yv.y; rv.z -= alpha * yv.z; rv.w -= alpha * yv.w;

    reinterpret_cast<float4*>(x)[i] = xv;
    reinterpret_cast<float4*>(r)[i] = rv;

    float v = rv.x * rv.x + rv.y * rv.y + rv.z * rv.z + rv.w * rv.w;
#pragma unroll
    for (int off = 32; off > 0; off >>= 1) v += __shfl_down(v, off);
    __shared__ float t1[4];
    if ((t & 63) == 0) t1[t >> 6] = v;
    __syncthreads();
    if (t == 0) rs_new8[blockIdx.x] = t1[0] + t1[1] + t1[2] + t1[3];
}

// ---------------------------------------------------------------------------
// ws layout: A16 (128 MiB, only upper tiles written/read) | diag32[N] y[N]
//            r[N] p0[N] p1[N] | pAp_s[2048] | pap32[32] | rs_arr[8*(ITERS+1)]
//            | ypart[64 * 8192]  (2 MiB)
// No atomics anywhere; every reduction has a code-fixed order; every ypart
// entry has a unique writer each iteration.
// ---------------------------------------------------------------------------
extern "C" void kernel_launch(void* const* d_in, const int* in_sizes, int n_in,
                              void* d_out, int out_size, void* d_ws, size_t ws_size,
                              hipStream_t stream) {
    const float* A = (const float*)d_in[0];
    const float* b = (const float*)d_in[1];
    float* x = (float*)d_out;

    __half* A16   = (__half*)d_ws;
    float* fb     = (float*)d_ws + (size_t)CG_N * CG_N / 2;
    float* diag32 = fb;
    float* y      = fb + CG_N;
    float* r      = fb + 2 * CG_N;
    float* p0     = fb + 3 * CG_N;
    float* p1     = fb + 4 * CG_N;
    float* pAp_s  = fb + 5 * CG_N;               // 2048
    float* pap32  = pAp_s + NW_CONV;             // 32
    float* rs_arr = pap32 + 32;                  // 8 * (CG_ITERS + 1)
    float* ypart  = rs_arr + 8 * (CG_ITERS + 1); // 64 * 8192

    cg_init_kernel<<<8, 256, 0, stream>>>(b, x, r, p0, &rs_arr[0]);

    // iteration 0: fp32 matvec + fp16 upper-triangle conversion (p = b)
    cg_matvec_convert<<<CONV_BLOCKS, 256, 0, stream>>>(A, A16, diag32, p0, y, pAp_s);
    cg_update_kernel<<<8, 256, 0, stream>>>(x, r, p0, y, pAp_s, NW_CONV,
                                            &rs_arr[0], &rs_arr[8]);

    for (int i = 1; i < CG_ITERS; ++i) {
        float* p_old = (i & 1) ? p0 : p1;
        float* p_new = (i & 1) ? p1 : p0;
        cg_matvec_ut<<<MV_BLOCKS, 256, 0, stream>>>(A16, r, p_old, p_new, ypart,
                                                    &rs_arr[8 * i],        // beta num
                                                    &rs_arr[8 * (i - 1)]); // beta den
        cg_assemble_kernel<<<32, 256, 0, stream>>>(ypart, diag32, p_new, y, pap32);
        cg_update_kernel<<<8, 256, 0, stream>>>(x, r, p_new, y, pap32, 32,
                                                &rs_arr[8 * i], &rs_arr[8 * (i + 1)]);
    }
}

// Round 9
// 440.991 us; speedup vs baseline: 1.6612x; 1.6612x over previous
//
#include <hip/hip_runtime.h>
#include <hip/hip_fp16.h>

#define CG_N      8192
#define CG_ITERS  10

// symmetric (upper-triangle) matvec geometry: one 128x128 tile per block
#define BAND      128
#define NBANDS    64                          // CG_N / BAND
#define NTILES    (NBANDS * (NBANDS + 1) / 2) // 2080 upper tiles

// convert kernel geometry (fp32 A, iteration 0)
#define RPW_C       4
#define WPB_C       4
#define CONV_BLOCKS (CG_N / (RPW_C * WPB_C))   // 512
#define NW_CONV     (CG_N / RPW_C)             // 2048 pAp slots

// ---------------------------------------------------------------------------
// x = 0, r = b, p = b, rs_part[block] = block partial of b.b  (plain stores)
// ---------------------------------------------------------------------------
__global__ __launch_bounds__(256) void cg_init_kernel(const float* __restrict__ b,
                                                      float* __restrict__ x,
                                                      float* __restrict__ r,
                                                      float* __restrict__ p,
                                                      float* __restrict__ rs_part) {
    const int i = blockIdx.x * 256 + threadIdx.x;   // float4 index
    const float4 bv = reinterpret_cast<const float4*>(b)[i];
    reinterpret_cast<float4*>(x)[i] = make_float4(0.f, 0.f, 0.f, 0.f);
    reinterpret_cast<float4*>(r)[i] = bv;
    reinterpret_cast<float4*>(p)[i] = bv;

    float v = bv.x * bv.x + bv.y * bv.y + bv.z * bv.z + bv.w * bv.w;
#pragma unroll
    for (int off = 32; off > 0; off >>= 1) v += __shfl_down(v, off);
    __shared__ float tmp[4];
    const int t = threadIdx.x;
    if ((t & 63) == 0) tmp[t >> 6] = v;
    __syncthreads();
    if (t == 0) rs_part[blockIdx.x] = tmp[0] + tmp[1] + tmp[2] + tmp[3];
}

__device__ __forceinline__ unsigned pack2h(float a, float b) {
    const __half2 h = __floats2half2_rn(a, b);
    return *reinterpret_cast<const unsigned*>(&h);
}

__device__ __forceinline__ float4 syn4(float beta, float4 pv, float4 rv) {
    float4 o;
    o.x = fmaf(beta, pv.x, rv.x); o.y = fmaf(beta, pv.y, rv.y);
    o.z = fmaf(beta, pv.z, rv.z); o.w = fmaf(beta, pv.w, rv.w);
    return o;
}

// ---------------------------------------------------------------------------
// Iteration-0 matvec (fp32 A) + conversion to fp16.
//   y = (A + 1e-6 I) p ; per-wave slot store of p.y
//   A16 written ONLY for upper-triangle tiles (col band >= row band);
//   diagonal extracted to fp32 diag32 and zeroed in A16.
// ---------------------------------------------------------------------------
__global__ __launch_bounds__(256) void cg_matvec_convert(const float* __restrict__ A,
                                                         __half* __restrict__ A16,
                                                         float* __restrict__ diag32,
                                                         const float* __restrict__ p,
                                                         float* __restrict__ y,
                                                         float* __restrict__ pAp_s) {
    const int t    = threadIdx.x;
    const int lane = t & 63;
    const int wid  = blockIdx.x * WPB_C + (t >> 6);   // 0..2047
    const int row0 = wid * RPW_C;

    const float4* __restrict__ p4 = reinterpret_cast<const float4*>(p);
    const float4* Arow4[RPW_C];
    uint4* A16row4[RPW_C];
#pragma unroll
    for (int q = 0; q < RPW_C; ++q) {
        Arow4[q]   = reinterpret_cast<const float4*>(A + (size_t)(row0 + q) * CG_N);
        A16row4[q] = reinterpret_cast<uint4*>(A16 + (size_t)(row0 + q) * CG_N);
    }

    float acc[RPW_C] = {0.f, 0.f, 0.f, 0.f};

#pragma unroll 1
    for (int k = 0; k < 16; ++k) {
        const int g = k * 64 + lane;               // column group, 8 cols
        const float4 pa = p4[2 * g], pb = p4[2 * g + 1];
#pragma unroll
        for (int q = 0; q < RPW_C; ++q) {
            float4 a = Arow4[q][2 * g];
            float4 b = Arow4[q][2 * g + 1];
            acc[q] += a.x * pa.x + a.y * pa.y + a.z * pa.z + a.w * pa.w +
                      b.x * pb.x + b.y * pb.y + b.z * pb.z + b.w * pb.w;
            const int row = row0 + q;
            if (k == (row >> 9) && lane == ((row >> 3) & 63)) {
                const int m = row & 7;
                const float d = (m == 0) ? a.x : (m == 1) ? a.y : (m == 2) ? a.z :
                                (m == 3) ? a.w : (m == 4) ? b.x : (m == 5) ? b.y :
                                (m == 6) ? b.z : b.w;
                diag32[row] = d + 1e-6f;
                if      (m == 0) a.x = 0.f; else if (m == 1) a.y = 0.f;
                else if (m == 2) a.z = 0.f; else if (m == 3) a.w = 0.f;
                else if (m == 4) b.x = 0.f; else if (m == 5) b.y = 0.f;
                else if (m == 6) b.z = 0.f; else               b.w = 0.f;
            }
            // write only upper-triangle tiles: col band (g>>4) >= row band (row>>7)
            if ((g >> 4) >= (row >> 7)) {
                uint4 hh;
                hh.x = pack2h(a.x, a.y); hh.y = pack2h(a.z, a.w);
                hh.z = pack2h(b.x, b.y); hh.w = pack2h(b.z, b.w);
                A16row4[q][g] = hh;
            }
        }
    }

#pragma unroll
    for (int q = 0; q < RPW_C; ++q)
#pragma unroll
        for (int off = 32; off > 0; off >>= 1) acc[q] += __shfl_down(acc[q], off);

    if (lane == 0) {
        float pAp = 0.f;
#pragma unroll
        for (int q = 0; q < RPW_C; ++q) {
            const int row = row0 + q;
            const float pv = p[row];
            const float yr = acc[q] + 1e-6f * pv;   // fp32 dot included true diag
            y[row] = yr;
            pAp += yr * pv;
        }
        pAp_s[wid] = pAp;      // unique slot — plain store, deterministic
    }
}

// ---------------------------------------------------------------------------
// Symmetric fp16 matvec, ONE 128x128 upper tile per block (grid = 2080):
//   beta  = sum(rs_num)/sum(rs_den)+eps   (fixed order)
//   p_new = r + beta*p_old  (blocks 0..255 write their designated 32-float slice)
//   forward:   ypart[bj][row in bi]  = A_tile   . p_new[cols of bj]
//   transpose: ypart[bi][col in bj]  = A_tile^T . p_new[rows of bi]  (bi<bj)
//   Entry ypart[c][idx] has exactly one writer -> deterministic.
// Wave layout: lane = rowsub*16 + cg; wave covers 32 rows (8 trips x 4 rows).
// ---------------------------------------------------------------------------
__global__ __launch_bounds__(256) void cg_matvec_ut(const __half* __restrict__ A16,
                                                    const float* __restrict__ r,
                                                    const float* __restrict__ p_old,
                                                    float* __restrict__ p_new,
                                                    float* __restrict__ ypart,
                                                    const float* __restrict__ rs_num,
                                                    const float* __restrict__ rs_den) {
    const int t      = threadIdx.x;
    const int lane   = t & 63;
    const int w      = t >> 6;         // wave 0..3
    const int rowsub = lane >> 4;      // 0..3
    const int cg     = lane & 15;      // col group (8 cols each)

    float num = 0.f, den = 0.f;
#pragma unroll
    for (int k = 0; k < 8; ++k) { num += rs_num[k]; den += rs_den[k]; }
    const float beta = num / (den + 1e-12f);

    const float4* __restrict__ r4  = reinterpret_cast<const float4*>(r);
    const float4* __restrict__ po4 = reinterpret_cast<const float4*>(p_old);

    // designated p_new writers: blocks 0..255, threads 0..7 -> all 2048 float4
    if (blockIdx.x < 256 && t < 8) {
        const int j = blockIdx.x * 8 + t;
        reinterpret_cast<float4*>(p_new)[j] = syn4(beta, po4[j], r4[j]);
    }

    // decode tile -> (bi, bj), bi <= bj
    int bi = 0, rem = blockIdx.x, rl = NBANDS;
    while (rem >= rl) { rem -= rl; --rl; ++bi; }
    const int bj = bi + rem;
    const int rb = bi * BAND, cb = bj * BAND;
    const bool diag = (bi == bj);

    // this lane's 8-col slice of p_new (synthesized)
    const int c4 = (cb >> 2) + cg * 2;
    const float4 pca = syn4(beta, po4[c4],     r4[c4]);
    const float4 pcb = syn4(beta, po4[c4 + 1], r4[c4 + 1]);

    float tc0=0.f,tc1=0.f,tc2=0.f,tc3=0.f,tc4=0.f,tc5=0.f,tc6=0.f,tc7=0.f;

    __shared__ float tsl[4][BAND];

#pragma unroll
    for (int tr = 0; tr < 8; ++tr) {
        const int row = rb + w * 32 + tr * 4 + rowsub;
        const uint4 av = *reinterpret_cast<const uint4*>(
            A16 + (size_t)row * CG_N + cb + cg * 8);
        const __half2* h2 = reinterpret_cast<const __half2*>(&av);
        const float2 f0 = __half22float2(h2[0]);
        const float2 f1 = __half22float2(h2[1]);
        const float2 f2 = __half22float2(h2[2]);
        const float2 f3 = __half22float2(h2[3]);

        float fwd = f0.x*pca.x + f0.y*pca.y + f1.x*pca.z + f1.y*pca.w
                  + f2.x*pcb.x + f2.y*pcb.y + f3.x*pcb.z + f3.y*pcb.w;
        fwd += __shfl_down(fwd, 8);
        fwd += __shfl_down(fwd, 4);
        fwd += __shfl_down(fwd, 2);
        fwd += __shfl_down(fwd, 1);
        if (cg == 0) ypart[(size_t)bj * CG_N + row] = fwd;

        if (!diag) {
            const float prow = fmaf(beta, p_old[row], r[row]);  // p_new[row]
            tc0 = fmaf(f0.x, prow, tc0); tc1 = fmaf(f0.y, prow, tc1);
            tc2 = fmaf(f1.x, prow, tc2); tc3 = fmaf(f1.y, prow, tc3);
            tc4 = fmaf(f2.x, prow, tc4); tc5 = fmaf(f2.y, prow, tc5);
            tc6 = fmaf(f3.x, prow, tc6); tc7 = fmaf(f3.y, prow, tc7);
        }
    }

    if (!diag) {   // block-uniform branch
        tc0 += __shfl_down(tc0, 32); tc0 += __shfl_down(tc0, 16);
        tc1 += __shfl_down(tc1, 32); tc1 += __shfl_down(tc1, 16);
        tc2 += __shfl_down(tc2, 32); tc2 += __shfl_down(tc2, 16);
        tc3 += __shfl_down(tc3, 32); tc3 += __shfl_down(tc3, 16);
        tc4 += __shfl_down(tc4, 32); tc4 += __shfl_down(tc4, 16);
        tc5 += __shfl_down(tc5, 32); tc5 += __shfl_down(tc5, 16);
        tc6 += __shfl_down(tc6, 32); tc6 += __shfl_down(tc6, 16);
        tc7 += __shfl_down(tc7, 32); tc7 += __shfl_down(tc7, 16);
        if (rowsub == 0) {
            float* d = &tsl[w][cg * 8];
            d[0]=tc0; d[1]=tc1; d[2]=tc2; d[3]=tc3;
            d[4]=tc4; d[5]=tc5; d[6]=tc6; d[7]=tc7;
        }
        __syncthreads();
        if (t < BAND)
            ypart[(size_t)bi * CG_N + cb + t] =
                tsl[0][t] + tsl[1][t] + tsl[2][t] + tsl[3][t];
    }
}

// ---------------------------------------------------------------------------
// Assemble y from the 64 per-band partials (fixed order) + diagonal term,
// and emit per-block pAp partials. grid: 32 blocks x 256 (one row/thread).
// ---------------------------------------------------------------------------
__global__ __launch_bounds__(256) void cg_assemble_kernel(const float* __restrict__ ypart,
                                                          const float* __restrict__ diag32,
                                                          const float* __restrict__ p,
                                                          float* __restrict__ y,
                                                          float* __restrict__ pap32) {
    const int row = blockIdx.x * 256 + threadIdx.x;
    float s = 0.f;
#pragma unroll
    for (int c = 0; c < NBANDS; ++c) s += ypart[(size_t)c * CG_N + row];
    const float pv = p[row];
    const float yr = fmaf(diag32[row], pv, s);
    y[row] = yr;

    float v = yr * pv;
#pragma unroll
    for (int off = 32; off > 0; off >>= 1) v += __shfl_down(v, off);
    __shared__ float tmp[4];
    if ((threadIdx.x & 63) == 0) tmp[threadIdx.x >> 6] = v;
    __syncthreads();
    if (threadIdx.x == 0) pap32[blockIdx.x] = tmp[0] + tmp[1] + tmp[2] + tmp[3];
}

// ---------------------------------------------------------------------------
// Update, fully deterministic, direct residual norm:
//   pAp   = fixed-order tree reduction of n_slots per-wave slots
//   rso   = fixed serial sum of rs_old8[0..8)
//   alpha = rso / (pAp + 1e-12)
//   x += alpha p ; r -= alpha y ; rs_new8[block] = block partial of r.r
// ---------------------------------------------------------------------------
__global__ __launch_bounds__(256) void cg_update_kernel(float* __restrict__ x,
                                                        float* __restrict__ r,
                                                        const float* __restrict__ p,
                                                        const float* __restrict__ y,
                                                        const float* __restrict__ pAp_s,
                                                        int n_slots,
                                                        const float* __restrict__ rs_old8,
                                                        float* __restrict__ rs_new8) {
    const int t = threadIdx.x;

    float a = 0.f;
    for (int k = t; k < n_slots; k += 256) a += pAp_s[k];   // fixed strided partials
#pragma unroll
    for (int off = 32; off > 0; off >>= 1) a += __shfl_down(a, off);
    __shared__ float t0[4];
    if ((t & 63) == 0) t0[t >> 6] = a;
    __syncthreads();
    const float pAp = t0[0] + t0[1] + t0[2] + t0[3];

    float rso = 0.f;
#pragma unroll
    for (int k = 0; k < 8; ++k) rso += rs_old8[k];
    const float alpha = rso / (pAp + 1e-12f);

    const int i = blockIdx.x * 256 + t;             // float4 index
    float4 xv = reinterpret_cast<float4*>(x)[i];
    float4 rv = reinterpret_cast<float4*>(r)[i];
    const float4 pv = reinterpret_cast<const float4*>(p)[i];
    const float4 yv = reinterpret_cast<const float4*>(y)[i];

    xv.x += alpha * pv.x; xv.y += alpha * pv.y; xv.z += alpha * pv.z; xv.w += alpha * pv.w;
    rv.x -= alpha * yv.x; rv.y -= alpha * yv.y; rv.z -= alpha * yv.z; rv.w -= alpha * yv.w;

    reinterpret_cast<float4*>(x)[i] = xv;
    reinterpret_cast<float4*>(r)[i] = rv;

    float v = rv.x * rv.x + rv.y * rv.y + rv.z * rv.z + rv.w * rv.w;
#pragma unroll
    for (int off = 32; off > 0; off >>= 1) v += __shfl_down(v, off);
    __shared__ float t1[4];
    if ((t & 63) == 0) t1[t >> 6] = v;
    __syncthreads();
    if (t == 0) rs_new8[blockIdx.x] = t1[0] + t1[1] + t1[2] + t1[3];
}

// ---------------------------------------------------------------------------
// ws layout: A16 (128 MiB, only upper tiles written/read) | diag32[N] y[N]
//            r[N] p0[N] p1[N] | pAp_s[2048] | pap32[32] | rs_arr[8*(ITERS+1)]
//            | ypart[64 * 8192]  (2 MiB)
// No atomics anywhere; every reduction has a code-fixed order; every ypart
// entry has a unique writer each iteration.
// ---------------------------------------------------------------------------
extern "C" void kernel_launch(void* const* d_in, const int* in_sizes, int n_in,
                              void* d_out, int out_size, void* d_ws, size_t ws_size,
                              hipStream_t stream) {
    const float* A = (const float*)d_in[0];
    const float* b = (const float*)d_in[1];
    float* x = (float*)d_out;

    __half* A16   = (__half*)d_ws;
    float* fb     = (float*)d_ws + (size_t)CG_N * CG_N / 2;
    float* diag32 = fb;
    float* y      = fb + CG_N;
    float* r      = fb + 2 * CG_N;
    float* p0     = fb + 3 * CG_N;
    float* p1     = fb + 4 * CG_N;
    float* pAp_s  = fb + 5 * CG_N;               // 2048
    float* pap32  = pAp_s + NW_CONV;             // 32
    float* rs_arr = pap32 + 32;                  // 8 * (CG_ITERS + 1)
    float* ypart  = rs_arr + 8 * (CG_ITERS + 1); // 64 * 8192

    cg_init_kernel<<<8, 256, 0, stream>>>(b, x, r, p0, &rs_arr[0]);

    // iteration 0: fp32 matvec + fp16 upper-triangle conversion (p = b)
    cg_matvec_convert<<<CONV_BLOCKS, 256, 0, stream>>>(A, A16, diag32, p0, y, pAp_s);
    cg_update_kernel<<<8, 256, 0, stream>>>(x, r, p0, y, pAp_s, NW_CONV,
                                            &rs_arr[0], &rs_arr[8]);

    for (int i = 1; i < CG_ITERS; ++i) {
        float* p_old = (i & 1) ? p0 : p1;
        float* p_new = (i & 1) ? p1 : p0;
        cg_matvec_ut<<<NTILES, 256, 0, stream>>>(A16, r, p_old, p_new, ypart,
                                                 &rs_arr[8 * i],        // beta num
                                                 &rs_arr[8 * (i - 1)]); // beta den
        cg_assemble_kernel<<<32, 256, 0, stream>>>(ypart, diag32, p_new, y, pap32);
        cg_update_kernel<<<8, 256, 0, stream>>>(x, r, p_new, y, pap32, 32,
                                                &rs_arr[8 * i], &rs_arr[8 * (i + 1)]);
    }
}